// Round 18
// baseline (63.964 us; speedup 1.0000x reference)
//
#include <hip/hip_runtime.h>
#include <hip/hip_bf16.h>

#define NB 4
#define SEQ 2048
#define DMODEL 1024
#define DKEY 128

using f32x4  = __attribute__((ext_vector_type(4))) float;
using bf16x8 = __attribute__((ext_vector_type(8))) short;           // 8 bf16 (4 VGPRs)
using u16x4  = __attribute__((ext_vector_type(4))) unsigned short;
using u16x8  = __attribute__((ext_vector_type(8))) unsigned short;

__device__ __forceinline__ unsigned short f2bf(float f) {
  __hip_bfloat16 h = __float2bfloat16(f);
  return __builtin_bit_cast(unsigned short, h);
}
// async 16B global->LDS; dest must be wave-uniform base + lane*16 (m104)
__device__ __forceinline__ void gload16(const void* g, void* l) {
  __builtin_amdgcn_global_load_lds(
      (const __attribute__((address_space(1))) void*)g,
      (__attribute__((address_space(3))) void*)l, 16, 0, 0);
}

// ---------------------------------------------------------------------------
// Projection, r9 math at 8 waves/block (TLP x2 — the one new variable):
//   Y[m][n] = sum_d X[m][d] * W[n][d]
// X fp32 [8192][1024], W fp32 [128][1024].
// z=0 (Q), z=1 (K): Y row-major bf16 [8192][128].
// z=2 (V): V TRANSPOSED per batch: Vt[b][d][s] bf16 [4][128][2048].
// BM=64 (384 blocks x 512 thr = 12 waves/CU, 3/SIMD — was 1.5/SIMD), BK=32,
// register double-buffer, ONE barrier per K-step. Wave w: rows (w>>1)*16,
// cols (w&1)*64, acc[4].
// MFMA conventions (m89/m92 HW-verified):
//   A: lane holds A[lane&15][(lane>>4)*8+j]   B: B[(lane>>4)*8+j][lane&15]
//   C/D: col = lane&15, row = (lane>>4)*4 + reg
// ---------------------------------------------------------------------------
__global__ __launch_bounds__(512) void proj_kernel(
    const float* __restrict__ Xq, const float* __restrict__ Xk, const float* __restrict__ Xv,
    const float* __restrict__ Wq, const float* __restrict__ Wk, const float* __restrict__ Wv,
    unsigned short* __restrict__ Yq, unsigned short* __restrict__ Yk,
    unsigned short* __restrict__ Vt)
{
  const int z = blockIdx.z;
  const float* X = (z == 0) ? Xq : (z == 1) ? Xk : Xv;
  const float* W = (z == 0) ? Wq : (z == 1) ? Wk : Wv;

  __shared__ alignas(16) unsigned short Xl[2][64][40];   // stride 80 B (5x16)
  __shared__ alignas(16) unsigned short Wl[2][128][40];
  __shared__ alignas(16) unsigned short Tl[128][72];     // z=2 transpose buffer

  const int t     = threadIdx.x;
  const int lane  = t & 63;
  const int w     = t >> 6;       // 0..7
  const int wr_   = w >> 1;       // row group (16 rows)
  const int wc_   = w & 1;        // col half (64 cols)
  const int lr    = lane & 15;
  const int lk    = (lane >> 4) * 8;
  const int rbase = (lane >> 4) * 4;
  const long m0   = (long)blockIdx.x * 64;

  f32x4 acc[4];
  const f32x4 zero = {0.f, 0.f, 0.f, 0.f};
#pragma unroll
  for (int n = 0; n < 4; ++n) acc[n] = zero;

  // staging: X 64x32 fp32 -> 1 float4/thread; W 128x32 fp32 -> 2 float4/thread
  const int xrow = t >> 3, xc4 = (t & 7) << 2;
  float4 xr = *reinterpret_cast<const float4*>(&X[(m0 + xrow) * DMODEL + xc4]);
  float4 wr4[2];
#pragma unroll
  for (int i = 0; i < 2; ++i) {
    int id = t + 512 * i, row = id >> 3, c4 = (id & 7) << 2;
    wr4[i] = *reinterpret_cast<const float4*>(&W[(long)row * DMODEL + c4]);
  }

  for (int ks = 0; ks < DMODEL / 32; ++ks) {
    const int cur = ks & 1;
    {
      u16x4 p = { f2bf(xr.x), f2bf(xr.y), f2bf(xr.z), f2bf(xr.w) };
      *reinterpret_cast<u16x4*>(&Xl[cur][xrow][xc4]) = p;
    }
#pragma unroll
    for (int i = 0; i < 2; ++i) {
      int id = t + 512 * i, row = id >> 3, c4 = (id & 7) << 2;
      u16x4 p = { f2bf(wr4[i].x), f2bf(wr4[i].y), f2bf(wr4[i].z), f2bf(wr4[i].w) };
      *reinterpret_cast<u16x4*>(&Wl[cur][row][c4]) = p;
    }
    if (ks + 1 < DMODEL / 32) {
      const int k0 = (ks + 1) * 32;
      xr = *reinterpret_cast<const float4*>(&X[(m0 + xrow) * DMODEL + k0 + xc4]);
#pragma unroll
      for (int i = 0; i < 2; ++i) {
        int id = t + 512 * i, row = id >> 3, c4 = (id & 7) << 2;
        wr4[i] = *reinterpret_cast<const float4*>(&W[(long)row * DMODEL + k0 + c4]);
      }
    }
    __syncthreads();

    bf16x8 a = *reinterpret_cast<const bf16x8*>(&Xl[cur][wr_ * 16 + lr][lk]);
#pragma unroll
    for (int n = 0; n < 4; ++n) {
      bf16x8 b = *reinterpret_cast<const bf16x8*>(&Wl[cur][wc_ * 64 + n * 16 + lr][lk]);
      acc[n] = __builtin_amdgcn_mfma_f32_16x16x32_bf16(a, b, acc[n], 0, 0, 0);
    }
  }

  if (z != 2) {
    unsigned short* Y = (z == 0) ? Yq : Yk;
#pragma unroll
    for (int n = 0; n < 4; ++n)
#pragma unroll
      for (int r = 0; r < 4; ++r) {
        long row = m0 + wr_ * 16 + rbase + r;
        Y[row * DKEY + wc_ * 64 + n * 16 + lr] = f2bf(acc[n][r]);
      }
  } else {
    // transpose epilogue: acc (64 s-rows x 128 d) -> Vt[b][d][s]
#pragma unroll
    for (int n = 0; n < 4; ++n)
#pragma unroll
      for (int r = 0; r < 4; ++r)
        Tl[wc_ * 64 + n * 16 + lr][wr_ * 16 + rbase + r] = f2bf(acc[n][r]);
    __syncthreads();
    const int bb = (int)(m0 >> 11);      // 2048 rows per batch
    const int s0 = (int)(m0 & 2047);
#pragma unroll
    for (int i = 0; i < 2; ++i) {
      int id = t + 512 * i;              // 1024 chunks of 8
      int dr = id >> 3;
      int c8 = (id & 7) << 3;
      u16x8 v = *reinterpret_cast<const u16x8*>(&Tl[dr][c8]);
      *reinterpret_cast<u16x8*>(&Vt[((size_t)bb * DKEY + dr) * SEQ + s0 + c8]) = v;
    }
  }
}

// ---------------------------------------------------------------------------
// Causal flash attention (round-15 version, UNCHANGED — async global_load_lds
// staging with SOURCE-side swizzle, LDS dest linear, rule #21):
// 256 blocks (1/CU) = 64 q-tiles(32 rows) x 4 batches. 8 waves = 4 KV-split
// groups x 2; group g stages K[64][128] + Vt[128][64]; 2 barriers/step
// (__syncthreads drains vmcnt for the DMA writes). In-register softmax,
// per-wave P, 4-way flash merge over K-LDS alias. Output fp32.
// ---------------------------------------------------------------------------
__global__ __launch_bounds__(512, 2) void attn_kernel(
    const unsigned short* __restrict__ Q,
    const unsigned short* __restrict__ K,
    const unsigned short* __restrict__ Vt,
    float* __restrict__ O)
{
  const int  L    = blockIdx.x;
  const int  b    = (L & 7) >> 1;                     // batch -> XCD pair
  const int  qt   = 63 - (((L >> 3) << 1) | (L & 1)); // long blocks first
  const int  q0   = qt * 32;
  const long base = (long)b * SEQ;
  const int  nt   = (q0 >> 6) + 1;                    // 64-wide KV tiles
  const int  nsteps = (nt + 3) >> 2;

  __shared__ alignas(16) unsigned short Kl[4][64][128];   // 64 KB (swizzled)
  __shared__ alignas(16) unsigned short Vl[4][128][64];   // 64 KB (swizzled)
  __shared__ alignas(16) unsigned short Plds[8][16][72];  // per-wave P (+8 pad)
  __shared__ float Sm[4][32], Sl[4][32];

  const int t     = threadIdx.x;
  const int lane  = t & 63;
  const int w     = t >> 6;      // 0..7
  const int g     = w >> 1;      // KV group 0..3
  const int wq    = w & 1;       // 16-row half within group
  const int lr    = lane & 15;
  const int hi    = lane >> 4;
  const int lk    = hi * 8;
  const int rbase = hi * 4;

  bf16x8 qa[4];
  {
    const long qrow = (base + q0 + wq * 16 + lr) * (long)DKEY;
#pragma unroll
    for (int dk = 0; dk < 4; ++dk)
      qa[dk] = *reinterpret_cast<const bf16x8*>(&Q[qrow + dk * 32 + lk]);
  }

  const f32x4 zero = {0.f, 0.f, 0.f, 0.f};
  f32x4 oacc[8];
#pragma unroll
  for (int n = 0; n < 8; ++n) oacc[n] = zero;
  float m_run[4], l_run[4];
#pragma unroll
  for (int r = 0; r < 4; ++r) { m_run[r] = -1e30f; l_run[r] = 0.0f; }

  const float sc = 0.08838834764831845f;  // 1/sqrt(128)
  const unsigned short* VtB = Vt + (size_t)b * DKEY * SEQ;

  for (int st = 0; st < nsteps; ++st) {
    const int kt  = st * 4 + g;
    const bool act = kt < nt;
    const int kv0 = kt * 64;

    if (act) {
      // K: dest granule c (row=c>>4, d=c&15) <- source granule d^(row&7)
      const unsigned short* Kp = K + (base + kv0) * (long)DKEY;
      char* Kd = (char*)(&Kl[g][0][0]);
#pragma unroll
      for (int it = 0; it < 8; ++it) {
        int c = it * 128 + wq * 64 + lane;
        int row = c >> 4, d = c & 15;
        int srcg = (c & ~15) | (d ^ (row & 7));
        gload16(&Kp[(size_t)srcg * 8], Kd + (size_t)c * 16);
      }
      // V: dest granule c (drow=c>>3, sl=c&7) <- source col granule sl^(drow&7)
      char* Vd = (char*)(&Vl[g][0][0]);
#pragma unroll
      for (int it = 0; it < 8; ++it) {
        int c = it * 128 + wq * 64 + lane;
        int drow = c >> 3, sl = c & 7;
        int srcc = (sl ^ (drow & 7)) << 3;
        gload16(&VtB[(size_t)drow * SEQ + kv0 + srcc], Vd + (size_t)c * 16);
      }
    }
    __syncthreads();   // drains vmcnt -> DMA writes visible

    if (act) {
      f32x4 s[4];
#pragma unroll
      for (int kc = 0; kc < 4; ++kc) {
        s[kc] = zero;
#pragma unroll
        for (int dk = 0; dk < 4; ++dk) {
          bf16x8 kb = *reinterpret_cast<const bf16x8*>(
              &Kl[g][kc * 16 + lr][((dk * 4 + hi) ^ (lr & 7)) * 8]);
          s[kc] = __builtin_amdgcn_mfma_f32_16x16x32_bf16(qa[dk], kb, s[kc], 0, 0, 0);
        }
      }

      const bool dmask = (kt == nt - 1);
      float x[4][4];
#pragma unroll
      for (int kc = 0; kc < 4; ++kc)
#pragma unroll
        for (int r = 0; r < 4; ++r) {
          float xv = s[kc][r] * sc;
          if (dmask) {
            int col  = kv0 + kc * 16 + lr;
            int rowq = q0 + wq * 16 + rbase + r;
            if (col > rowq) xv = -1e30f;
          }
          x[kc][r] = xv;
        }

#pragma unroll
      for (int r = 0; r < 4; ++r) {
        float tm = fmaxf(fmaxf(x[0][r], x[1][r]), fmaxf(x[2][r], x[3][r]));
        tm = fmaxf(tm, __shfl_xor(tm, 1));
        tm = fmaxf(tm, __shfl_xor(tm, 2));
        tm = fmaxf(tm, __shfl_xor(tm, 4));
        tm = fmaxf(tm, __shfl_xor(tm, 8));
        float mnew = fmaxf(m_run[r], tm);
        float scl  = __expf(m_run[r] - mnew);
        m_run[r] = mnew;
        float ps = 0.0f;
#pragma unroll
        for (int kc = 0; kc < 4; ++kc) {
          float pp = __expf(x[kc][r] - mnew);
          ps += pp;
          Plds[w][rbase + r][kc * 16 + lr] = f2bf(pp);
        }
        ps += __shfl_xor(ps, 1);
        ps += __shfl_xor(ps, 2);
        ps += __shfl_xor(ps, 4);
        ps += __shfl_xor(ps, 8);
        l_run[r] = l_run[r] * scl + ps;
#pragma unroll
        for (int n = 0; n < 8; ++n) oacc[n][r] *= scl;
      }

#pragma unroll
      for (int kk = 0; kk < 2; ++kk) {
        bf16x8 pa = *reinterpret_cast<const bf16x8*>(&Plds[w][lr][kk * 32 + lk]);
#pragma unroll
        for (int n = 0; n < 8; ++n) {
          bf16x8 vb = *reinterpret_cast<const bf16x8*>(
              &Vl[g][n * 16 + lr][((kk * 4 + hi) ^ (lr & 7)) * 8]);
          oacc[n] = __builtin_amdgcn_mfma_f32_16x16x32_bf16(pa, vb, oacc[n], 0, 0, 0);
        }
      }
    }
    __syncthreads();
  }

  float* Om = reinterpret_cast<float*>(&Kl[0][0][0]);   // [4][32][128] alias
#pragma unroll
  for (int n = 0; n < 8; ++n)
#pragma unroll
    for (int r = 0; r < 4; ++r)
      Om[(g * 32 + wq * 16 + rbase + r) * 128 + n * 16 + lr] = oacc[n][r];
  if (lr == 0) {
#pragma unroll
    for (int r = 0; r < 4; ++r) {
      Sm[g][wq * 16 + rbase + r] = m_run[r];
      Sl[g][wq * 16 + rbase + r] = l_run[r];
    }
  }
  __syncthreads();

  const int row = t >> 4;          // 0..31
  const int c0  = (t & 15) * 8;    // 0..120
  float mM = fmaxf(fmaxf(Sm[0][row], Sm[1][row]), fmaxf(Sm[2][row], Sm[3][row]));
  float wts[4], lsum = 0.0f;
#pragma unroll
  for (int gv = 0; gv < 4; ++gv) {
    wts[gv] = __expf(Sm[gv][row] - mM);
    lsum += wts[gv] * Sl[gv][row];
  }
  const float linv = 1.0f / lsum;
  f32x4 o0 = zero, o1 = zero;
#pragma unroll
  for (int gv = 0; gv < 4; ++gv) {
    const float* src = &Om[(gv * 32 + row) * 128 + c0];
    f32x4 a0 = *reinterpret_cast<const f32x4*>(src);
    f32x4 a1 = *reinterpret_cast<const f32x4*>(src + 4);
    const float wt = wts[gv];
#pragma unroll
    for (int j = 0; j < 4; ++j) { o0[j] += wt * a0[j]; o1[j] += wt * a1[j]; }
  }
#pragma unroll
  for (int j = 0; j < 4; ++j) { o0[j] *= linv; o1[j] *= linv; }
  float* op = &O[(base + q0 + row) * (long)DKEY + c0];
  *reinterpret_cast<f32x4*>(op)     = o0;
  *reinterpret_cast<f32x4*>(op + 4) = o1;
}

extern "C" void kernel_launch(void* const* d_in, const int* in_sizes, int n_in,
                              void* d_out, int out_size, void* d_ws, size_t ws_size,
                              hipStream_t stream) {
  const float* Xq = (const float*)d_in[0];
  const float* Xk = (const float*)d_in[1];
  const float* Xv = (const float*)d_in[2];
  // d_in[3] = mask: tril by construction; causality handled analytically.
  const float* Wq = (const float*)d_in[4];
  const float* Wk = (const float*)d_in[5];
  const float* Wv = (const float*)d_in[6];

  // ws layout: Q (2MB), K (2MB), V^T (2MB) bf16. ws >= 6MB (round-1 evidence).
  unsigned short* qp  = (unsigned short*)d_ws;
  unsigned short* kp  = qp + (size_t)NB * SEQ * DKEY;
  unsigned short* vtp = kp + (size_t)NB * SEQ * DKEY;

  dim3 g1(SEQ * NB / 64, 1, 3);   // 128 x 3 = 384 blocks x 512 thr
  hipLaunchKernelGGL(proj_kernel, g1, dim3(512), 0, stream,
                     Xq, Xk, Xv, Wq, Wk, Wv, qp, kp, vtp);
  hipLaunchKernelGGL(attn_kernel, dim3(256), dim3(512), 0, stream,
                     qp, kp, vtp, (float*)d_out);
}

// Round 19
// 58.650 us; speedup vs baseline: 1.0906x; 1.0906x over previous
//
#include <hip/hip_runtime.h>
#include <hip/hip_bf16.h>

#define NB 4
#define SEQ 2048
#define DMODEL 1024
#define DKEY 128

using f32x4  = __attribute__((ext_vector_type(4))) float;
using bf16x8 = __attribute__((ext_vector_type(8))) short;           // 8 bf16 (4 VGPRs)
using u16x4  = __attribute__((ext_vector_type(4))) unsigned short;
using u16x8  = __attribute__((ext_vector_type(8))) unsigned short;

__device__ __forceinline__ unsigned short f2bf(float f) {
  __hip_bfloat16 h = __float2bfloat16(f);
  return __builtin_bit_cast(unsigned short, h);
}
// async 16B global->LDS; dest must be wave-uniform base + lane*16 (m104)
__device__ __forceinline__ void gload16(const void* g, void* l) {
  __builtin_amdgcn_global_load_lds(
      (const __attribute__((address_space(1))) void*)g,
      (__attribute__((address_space(3))) void*)l, 16, 0, 0);
}

// ---------------------------------------------------------------------------
// Projection (round-9 proven version): Y[m][n] = sum_d X[m][d]*W[n][d]
// X fp32 [8192][1024], W fp32 [128][1024].
// z=0 (Q), z=1 (K): Y row-major bf16 [8192][128].
// z=2 (V): V TRANSPOSED per batch: Vt[b][d][s] bf16 [4][128][2048].
// BM=64 (384 blocks), BK=32, register double-buffer, ONE barrier per K-step.
// MFMA conventions (m89/m92 HW-verified):
//   A: lane holds A[lane&15][(lane>>4)*8+j]   B: B[(lane>>4)*8+j][lane&15]
//   C/D: col = lane&15, row = (lane>>4)*4 + reg
// ---------------------------------------------------------------------------
__global__ __launch_bounds__(256) void proj_kernel(
    const float* __restrict__ Xq, const float* __restrict__ Xk, const float* __restrict__ Xv,
    const float* __restrict__ Wq, const float* __restrict__ Wk, const float* __restrict__ Wv,
    unsigned short* __restrict__ Yq, unsigned short* __restrict__ Yk,
    unsigned short* __restrict__ Vt)
{
  const int z = blockIdx.z;
  const float* X = (z == 0) ? Xq : (z == 1) ? Xk : Xv;
  const float* W = (z == 0) ? Wq : (z == 1) ? Wk : Wv;

  __shared__ alignas(16) unsigned short Xl[2][64][40];   // stride 80 B (5x16)
  __shared__ alignas(16) unsigned short Wl[2][128][40];
  __shared__ alignas(16) unsigned short Tl[128][72];     // z=2 transpose buffer

  const int t     = threadIdx.x;
  const int lane  = t & 63;
  const int w     = t >> 6;
  const int lr    = lane & 15;
  const int lk    = (lane >> 4) * 8;
  const int rbase = (lane >> 4) * 4;
  const long m0   = (long)blockIdx.x * 64;

  f32x4 acc[8];
  const f32x4 zero = {0.f, 0.f, 0.f, 0.f};
#pragma unroll
  for (int n = 0; n < 8; ++n) acc[n] = zero;

  float4 xr[2], wr[4];
#pragma unroll
  for (int i = 0; i < 2; ++i) {
    int id = t + 256 * i, row = id >> 3, c4 = (id & 7) << 2;
    xr[i] = *reinterpret_cast<const float4*>(&X[(m0 + row) * DMODEL + c4]);
  }
#pragma unroll
  for (int i = 0; i < 4; ++i) {
    int id = t + 256 * i, row = id >> 3, c4 = (id & 7) << 2;
    wr[i] = *reinterpret_cast<const float4*>(&W[(long)row * DMODEL + c4]);
  }

  for (int ks = 0; ks < DMODEL / 32; ++ks) {
    const int cur = ks & 1;
#pragma unroll
    for (int i = 0; i < 2; ++i) {
      int id = t + 256 * i, row = id >> 3, c4 = (id & 7) << 2;
      u16x4 p = { f2bf(xr[i].x), f2bf(xr[i].y), f2bf(xr[i].z), f2bf(xr[i].w) };
      *reinterpret_cast<u16x4*>(&Xl[cur][row][c4]) = p;
    }
#pragma unroll
    for (int i = 0; i < 4; ++i) {
      int id = t + 256 * i, row = id >> 3, c4 = (id & 7) << 2;
      u16x4 p = { f2bf(wr[i].x), f2bf(wr[i].y), f2bf(wr[i].z), f2bf(wr[i].w) };
      *reinterpret_cast<u16x4*>(&Wl[cur][row][c4]) = p;
    }
    if (ks + 1 < DMODEL / 32) {
      const int k0 = (ks + 1) * 32;
#pragma unroll
      for (int i = 0; i < 2; ++i) {
        int id = t + 256 * i, row = id >> 3, c4 = (id & 7) << 2;
        xr[i] = *reinterpret_cast<const float4*>(&X[(m0 + row) * DMODEL + k0 + c4]);
      }
#pragma unroll
      for (int i = 0; i < 4; ++i) {
        int id = t + 256 * i, row = id >> 3, c4 = (id & 7) << 2;
        wr[i] = *reinterpret_cast<const float4*>(&W[(long)row * DMODEL + k0 + c4]);
      }
    }
    __syncthreads();

    bf16x8 a = *reinterpret_cast<const bf16x8*>(&Xl[cur][w * 16 + lr][lk]);
#pragma unroll
    for (int n = 0; n < 8; ++n) {
      bf16x8 b = *reinterpret_cast<const bf16x8*>(&Wl[cur][n * 16 + lr][lk]);
      acc[n] = __builtin_amdgcn_mfma_f32_16x16x32_bf16(a, b, acc[n], 0, 0, 0);
    }
  }

  if (z != 2) {
    unsigned short* Y = (z == 0) ? Yq : Yk;
#pragma unroll
    for (int n = 0; n < 8; ++n)
#pragma unroll
      for (int r = 0; r < 4; ++r) {
        long row = m0 + w * 16 + rbase + r;
        Y[row * DKEY + n * 16 + lr] = f2bf(acc[n][r]);
      }
  } else {
    // transpose epilogue: acc (64 s-rows x 128 d) -> Vt[b][d][s]
#pragma unroll
    for (int n = 0; n < 8; ++n)
#pragma unroll
      for (int r = 0; r < 4; ++r)
        Tl[n * 16 + lr][w * 16 + rbase + r] = f2bf(acc[n][r]);
    __syncthreads();
    const int bb = (int)(m0 >> 11);      // 2048 rows per batch
    const int s0 = (int)(m0 & 2047);
#pragma unroll
    for (int i = 0; i < 4; ++i) {
      int id = t + 256 * i;              // 1024 chunks of 8
      int dr = id >> 3;
      int c8 = (id & 7) << 3;
      u16x8 v = *reinterpret_cast<const u16x8*>(&Tl[dr][c8]);
      *reinterpret_cast<u16x8*>(&Vt[((size_t)bb * DKEY + dr) * SEQ + s0 + c8]) = v;
    }
  }
}

// ---------------------------------------------------------------------------
// Causal flash attention (round-15 version — async global_load_lds staging
// with SOURCE-side swizzle, LDS dest linear, rule #21):
// 256 blocks (1/CU) = 64 q-tiles(32 rows) x 4 batches. 8 waves = 4 KV-split
// groups x 2; group g stages K[64][128] + Vt[128][64]; 2 barriers/step
// (__syncthreads drains vmcnt for the DMA writes). In-register softmax,
// per-wave P, 4-way flash merge over K-LDS alias. Output fp32.
// LDS content: Kl[row][d] = K[row][d^(row&7)] (granule of 8 u16),
// Vl[d][s] = Vt[d][s^(d&7)]; read side uses the same involution.
// ---------------------------------------------------------------------------
__global__ __launch_bounds__(512, 2) void attn_kernel(
    const unsigned short* __restrict__ Q,
    const unsigned short* __restrict__ K,
    const unsigned short* __restrict__ Vt,
    float* __restrict__ O)
{
  const int  L    = blockIdx.x;
  const int  b    = (L & 7) >> 1;                     // batch -> XCD pair
  const int  qt   = 63 - (((L >> 3) << 1) | (L & 1)); // long blocks first
  const int  q0   = qt * 32;
  const long base = (long)b * SEQ;
  const int  nt   = (q0 >> 6) + 1;                    // 64-wide KV tiles
  const int  nsteps = (nt + 3) >> 2;

  __shared__ alignas(16) unsigned short Kl[4][64][128];   // 64 KB (swizzled)
  __shared__ alignas(16) unsigned short Vl[4][128][64];   // 64 KB (swizzled)
  __shared__ alignas(16) unsigned short Plds[8][16][72];  // per-wave P (+8 pad)
  __shared__ float Sm[4][32], Sl[4][32];

  const int t     = threadIdx.x;
  const int lane  = t & 63;
  const int w     = t >> 6;      // 0..7
  const int g     = w >> 1;      // KV group 0..3
  const int wq    = w & 1;       // 16-row half within group
  const int lr    = lane & 15;
  const int hi    = lane >> 4;
  const int lk    = hi * 8;
  const int rbase = hi * 4;

  bf16x8 qa[4];
  {
    const long qrow = (base + q0 + wq * 16 + lr) * (long)DKEY;
#pragma unroll
    for (int dk = 0; dk < 4; ++dk)
      qa[dk] = *reinterpret_cast<const bf16x8*>(&Q[qrow + dk * 32 + lk]);
  }

  const f32x4 zero = {0.f, 0.f, 0.f, 0.f};
  f32x4 oacc[8];
#pragma unroll
  for (int n = 0; n < 8; ++n) oacc[n] = zero;
  float m_run[4], l_run[4];
#pragma unroll
  for (int r = 0; r < 4; ++r) { m_run[r] = -1e30f; l_run[r] = 0.0f; }

  const float sc = 0.08838834764831845f;  // 1/sqrt(128)
  const unsigned short* VtB = Vt + (size_t)b * DKEY * SEQ;

  for (int st = 0; st < nsteps; ++st) {
    const int kt  = st * 4 + g;
    const bool act = kt < nt;
    const int kv0 = kt * 64;

    if (act) {
      // K: dest granule c (row=c>>4, d=c&15) <- source granule d^(row&7).
      // dest = &Kl[g] + c*16B = wave-uniform + lane*16 (c = it*128+wq*64+lane).
      const unsigned short* Kp = K + (base + kv0) * (long)DKEY;
      char* Kd = (char*)(&Kl[g][0][0]);
#pragma unroll
      for (int it = 0; it < 8; ++it) {
        int c = it * 128 + wq * 64 + lane;
        int row = c >> 4, d = c & 15;
        int srcg = (c & ~15) | (d ^ (row & 7));
        gload16(&Kp[(size_t)srcg * 8], Kd + (size_t)c * 16);
      }
      // V: dest granule c (drow=c>>3, sl=c&7) <- source col granule sl^(drow&7)
      char* Vd = (char*)(&Vl[g][0][0]);
#pragma unroll
      for (int it = 0; it < 8; ++it) {
        int c = it * 128 + wq * 64 + lane;
        int drow = c >> 3, sl = c & 7;
        int srcc = (sl ^ (drow & 7)) << 3;
        gload16(&VtB[(size_t)drow * SEQ + kv0 + srcc], Vd + (size_t)c * 16);
      }
    }
    __syncthreads();   // drains vmcnt -> DMA writes visible

    if (act) {
      f32x4 s[4];
#pragma unroll
      for (int kc = 0; kc < 4; ++kc) {
        s[kc] = zero;
#pragma unroll
        for (int dk = 0; dk < 4; ++dk) {
          bf16x8 kb = *reinterpret_cast<const bf16x8*>(
              &Kl[g][kc * 16 + lr][((dk * 4 + hi) ^ (lr & 7)) * 8]);
          s[kc] = __builtin_amdgcn_mfma_f32_16x16x32_bf16(qa[dk], kb, s[kc], 0, 0, 0);
        }
      }

      const bool dmask = (kt == nt - 1);
      float x[4][4];
#pragma unroll
      for (int kc = 0; kc < 4; ++kc)
#pragma unroll
        for (int r = 0; r < 4; ++r) {
          float xv = s[kc][r] * sc;
          if (dmask) {
            int col  = kv0 + kc * 16 + lr;
            int rowq = q0 + wq * 16 + rbase + r;
            if (col > rowq) xv = -1e30f;
          }
          x[kc][r] = xv;
        }

#pragma unroll
      for (int r = 0; r < 4; ++r) {
        float tm = fmaxf(fmaxf(x[0][r], x[1][r]), fmaxf(x[2][r], x[3][r]));
        tm = fmaxf(tm, __shfl_xor(tm, 1));
        tm = fmaxf(tm, __shfl_xor(tm, 2));
        tm = fmaxf(tm, __shfl_xor(tm, 4));
        tm = fmaxf(tm, __shfl_xor(tm, 8));
        float mnew = fmaxf(m_run[r], tm);
        float scl  = __expf(m_run[r] - mnew);
        m_run[r] = mnew;
        float ps = 0.0f;
#pragma unroll
        for (int kc = 0; kc < 4; ++kc) {
          float pp = __expf(x[kc][r] - mnew);
          ps += pp;
          Plds[w][rbase + r][kc * 16 + lr] = f2bf(pp);
        }
        ps += __shfl_xor(ps, 1);
        ps += __shfl_xor(ps, 2);
        ps += __shfl_xor(ps, 4);
        ps += __shfl_xor(ps, 8);
        l_run[r] = l_run[r] * scl + ps;
#pragma unroll
        for (int n = 0; n < 8; ++n) oacc[n][r] *= scl;
      }

#pragma unroll
      for (int kk = 0; kk < 2; ++kk) {
        bf16x8 pa = *reinterpret_cast<const bf16x8*>(&Plds[w][lr][kk * 32 + lk]);
#pragma unroll
        for (int n = 0; n < 8; ++n) {
          bf16x8 vb = *reinterpret_cast<const bf16x8*>(
              &Vl[g][n * 16 + lr][((kk * 4 + hi) ^ (lr & 7)) * 8]);
          oacc[n] = __builtin_amdgcn_mfma_f32_16x16x32_bf16(pa, vb, oacc[n], 0, 0, 0);
        }
      }
    }
    __syncthreads();
  }

  float* Om = reinterpret_cast<float*>(&Kl[0][0][0]);   // [4][32][128] alias
#pragma unroll
  for (int n = 0; n < 8; ++n)
#pragma unroll
    for (int r = 0; r < 4; ++r)
      Om[(g * 32 + wq * 16 + rbase + r) * 128 + n * 16 + lr] = oacc[n][r];
  if (lr == 0) {
#pragma unroll
    for (int r = 0; r < 4; ++r) {
      Sm[g][wq * 16 + rbase + r] = m_run[r];
      Sl[g][wq * 16 + rbase + r] = l_run[r];
    }
  }
  __syncthreads();

  const int row = t >> 4;          // 0..31
  const int c0  = (t & 15) * 8;    // 0..120
  float mM = fmaxf(fmaxf(Sm[0][row], Sm[1][row]), fmaxf(Sm[2][row], Sm[3][row]));
  float wts[4], lsum = 0.0f;
#pragma unroll
  for (int gv = 0; gv < 4; ++gv) {
    wts[gv] = __expf(Sm[gv][row] - mM);
    lsum += wts[gv] * Sl[gv][row];
  }
  const float linv = 1.0f / lsum;
  f32x4 o0 = zero, o1 = zero;
#pragma unroll
  for (int gv = 0; gv < 4; ++gv) {
    const float* src = &Om[(gv * 32 + row) * 128 + c0];
    f32x4 a0 = *reinterpret_cast<const f32x4*>(src);
    f32x4 a1 = *reinterpret_cast<const f32x4*>(src + 4);
    const float wt = wts[gv];
#pragma unroll
    for (int j = 0; j < 4; ++j) { o0[j] += wt * a0[j]; o1[j] += wt * a1[j]; }
  }
#pragma unroll
  for (int j = 0; j < 4; ++j) { o0[j] *= linv; o1[j] *= linv; }
  float* op = &O[(base + q0 + row) * (long)DKEY + c0];
  *reinterpret_cast<f32x4*>(op)     = o0;
  *reinterpret_cast<f32x4*>(op + 4) = o1;
}

extern "C" void kernel_launch(void* const* d_in, const int* in_sizes, int n_in,
                              void* d_out, int out_size, void* d_ws, size_t ws_size,
                              hipStream_t stream) {
  const float* Xq = (const float*)d_in[0];
  const float* Xk = (const float*)d_in[1];
  const float* Xv = (const float*)d_in[2];
  // d_in[3] = mask: tril by construction; causality handled analytically.
  const float* Wq = (const float*)d_in[4];
  const float* Wk = (const float*)d_in[5];
  const float* Wv = (const float*)d_in[6];

  // ws layout: Q (2MB), K (2MB), V^T (2MB) bf16. ws >= 6MB (round-1 evidence).
  unsigned short* qp  = (unsigned short*)d_ws;
  unsigned short* kp  = qp + (size_t)NB * SEQ * DKEY;
  unsigned short* vtp = kp + (size_t)NB * SEQ * DKEY;

  dim3 g1(SEQ * NB / 64, 1, 3);   // 128 x 3
  hipLaunchKernelGGL(proj_kernel, g1, dim3(256), 0, stream,
                     Xq, Xk, Xv, Wq, Wk, Wv, qp, kp, vtp);
  hipLaunchKernelGGL(attn_kernel, dim3(256), dim3(512), 0, stream,
                     qp, kp, vtp, (float*)d_out);
}